// Round 2
// baseline (342.360 us; speedup 1.0000x reference)
//
#include <hip/hip_runtime.h>

// TestEBCModel: jagged embedding gather + SUM pool (T=4,B=8192,L=50,VOCAB=100000,D=128)
// followed by 3 stacked Linear(D,D) with no activation.
// Key insight: the MLP is affine -> precompute M = W1^T W2^T W3^T and
// c = (b1 W2^T + b2) W3^T + b3, then fuse pooling + single matvec per row.
// R2: phase-1 gather = one row per WAVE, float2 per lane (full 512B row per
// instruction), unroll 8 -> 4KB in flight per wave, no divergence.

#define T_ 4
#define B_ 8192
#define L_ 50
#define VOCAB_ 100000
#define D_ 128
#define ROWS 16        // rows per block in fused kernel
#define PSTRIDE 20     // padded LDS stride for transposed pooled tile

// ws layout (floats): A1[16384] | c1[128] | M[16384] | c[128]  (~132 KB)
#define WS_A1 0
#define WS_C1 16384
#define WS_M  16512
#define WS_C  32896

// ---- stage 1: A1 = W1^T @ W2^T ; c1 = b1 @ W2^T + b2 ----
__global__ __launch_bounds__(128) void combine1(const float* __restrict__ W1,
                                                const float* __restrict__ W2,
                                                const float* __restrict__ b1,
                                                const float* __restrict__ b2,
                                                float* __restrict__ ws) {
  const int j = threadIdx.x;
  const int i = blockIdx.x;
  if (i < D_) {
    float acc = 0.f;
    for (int k = 0; k < D_; ++k)
      acc += W1[k * D_ + i] * W2[j * D_ + k];   // A1[i][j] = sum_k W1[k][i] W2[j][k]
    ws[WS_A1 + i * D_ + j] = acc;
  } else {
    float acc = b2[j];
    for (int k = 0; k < D_; ++k)
      acc += b1[k] * W2[j * D_ + k];            // c1[j]
    ws[WS_C1 + j] = acc;
  }
}

// ---- stage 2: M = A1 @ W3^T ; c = c1 @ W3^T + b3 ----
__global__ __launch_bounds__(128) void combine2(const float* __restrict__ W3,
                                                const float* __restrict__ b3,
                                                const float* __restrict__ ws_in,
                                                float* __restrict__ ws) {
  const int j = threadIdx.x;
  const int i = blockIdx.x;
  if (i < D_) {
    float acc = 0.f;
    for (int k = 0; k < D_; ++k)
      acc += ws_in[WS_A1 + i * D_ + k] * W3[j * D_ + k];  // M[i][j]
    ws[WS_M + i * D_ + j] = acc;
  } else {
    float acc = b3[j];
    for (int k = 0; k < D_; ++k)
      acc += ws_in[WS_C1 + k] * W3[j * D_ + k];           // c[j]
    ws[WS_C + j] = acc;
  }
}

// ---- fused: pool 16 rows, then out[g][j] = c[j] + sum_i pooled[g][i]*M[i][j] ----
__global__ __launch_bounds__(256) void fused(const int* __restrict__ indices,
                                             const int* __restrict__ lengths,
                                             const float* __restrict__ tables,
                                             const float* __restrict__ ws,
                                             float* __restrict__ out) {
  __shared__ __align__(16) float pooledT[D_][PSTRIDE];  // [i][r], stride 20 keeps float4 16B-aligned
  __shared__ int   idx_sh[ROWS][L_];
  __shared__ float c_sh[D_];
  __shared__ int   len_sh[ROWS];

  const int tid = threadIdx.x;
  const int g0  = blockIdx.x * ROWS;

  // stage indices / lengths / bias
  for (int k = tid; k < ROWS * L_; k += 256)
    idx_sh[k / L_][k % L_] = indices[g0 * L_ + k];
  if (tid < D_)   c_sh[tid]  = ws[WS_C + tid];
  if (tid < ROWS) len_sh[tid] = lengths[g0 + tid];
  __syncthreads();

  // phase 1: one row per wave, float2 per lane -> one gather instr = full 512B row.
  // unroll 8 -> up to 8 x 512B = 4KB in flight per wave.
  {
    const int lane = tid & 63;
    const int wv   = tid >> 6;            // 0..3, wave-uniform
    const int d0   = lane * 2;
    const int t    = g0 >> 13;            // table id; block never spans tables (16 | 8192)
    const float* __restrict__ tab = tables + (size_t)t * (VOCAB_ * D_) + d0;

    for (int q = 0; q < ROWS / 4; ++q) {
      const int r   = wv * 4 + q;
      const int len = len_sh[r];
      const int* __restrict__ il = idx_sh[r];
      float ax = 0.f, ay = 0.f;
      int l = 0;
      for (; l + 7 < len; l += 8) {
        const int i0 = il[l + 0], i1 = il[l + 1], i2 = il[l + 2], i3 = il[l + 3];
        const int i4 = il[l + 4], i5 = il[l + 5], i6 = il[l + 6], i7 = il[l + 7];
        const float2 v0 = *(const float2*)(tab + (size_t)i0 * D_);
        const float2 v1 = *(const float2*)(tab + (size_t)i1 * D_);
        const float2 v2 = *(const float2*)(tab + (size_t)i2 * D_);
        const float2 v3 = *(const float2*)(tab + (size_t)i3 * D_);
        const float2 v4 = *(const float2*)(tab + (size_t)i4 * D_);
        const float2 v5 = *(const float2*)(tab + (size_t)i5 * D_);
        const float2 v6 = *(const float2*)(tab + (size_t)i6 * D_);
        const float2 v7 = *(const float2*)(tab + (size_t)i7 * D_);
        ax += v0.x; ay += v0.y;  ax += v1.x; ay += v1.y;
        ax += v2.x; ay += v2.y;  ax += v3.x; ay += v3.y;
        ax += v4.x; ay += v4.y;  ax += v5.x; ay += v5.y;
        ax += v6.x; ay += v6.y;  ax += v7.x; ay += v7.y;
      }
      for (; l + 1 < len; l += 2) {
        const float2 va = *(const float2*)(tab + (size_t)il[l] * D_);
        const float2 vb = *(const float2*)(tab + (size_t)il[l + 1] * D_);
        ax += va.x; ay += va.y;  ax += vb.x; ay += vb.y;
      }
      if (l < len) {
        const float2 v = *(const float2*)(tab + (size_t)il[l] * D_);
        ax += v.x; ay += v.y;
      }
      pooledT[d0][r]     = ax;
      pooledT[d0 + 1][r] = ay;
    }
  }
  __syncthreads();

  // phase 2: matvec with precomposed M — per i: 1 coalesced M load (wave reads 256B),
  // 2 broadcast ds_read_b128 of pooled, 8 FMAs.
  const int j = tid & (D_ - 1);
  const int rbase = (tid >> 7) * 8;
  const float* Mg = ws + WS_M;
  float acc[8];
#pragma unroll
  for (int r = 0; r < 8; ++r) acc[r] = c_sh[j];
#pragma unroll 4
  for (int i = 0; i < D_; ++i) {
    const float m = Mg[i * D_ + j];
    const float4 p0 = *(const float4*)&pooledT[i][rbase];
    const float4 p1 = *(const float4*)&pooledT[i][rbase + 4];
    acc[0] += p0.x * m; acc[1] += p0.y * m; acc[2] += p0.z * m; acc[3] += p0.w * m;
    acc[4] += p1.x * m; acc[5] += p1.y * m; acc[6] += p1.z * m; acc[7] += p1.w * m;
  }
#pragma unroll
  for (int r = 0; r < 8; ++r)
    out[(size_t)(g0 + rbase + r) * D_ + j] = acc[r];
}

extern "C" void kernel_launch(void* const* d_in, const int* in_sizes, int n_in,
                              void* d_out, int out_size, void* d_ws, size_t ws_size,
                              hipStream_t stream) {
  const int*   indices = (const int*)d_in[0];
  const int*   lengths = (const int*)d_in[1];
  const float* tables  = (const float*)d_in[2];
  const float* W1      = (const float*)d_in[3];
  const float* b1      = (const float*)d_in[4];
  const float* W2      = (const float*)d_in[5];
  const float* b2      = (const float*)d_in[6];
  const float* W3      = (const float*)d_in[7];
  const float* b3      = (const float*)d_in[8];
  float*       out     = (float*)d_out;
  float*       ws      = (float*)d_ws;

  combine1<<<D_ + 1, D_, 0, stream>>>(W1, W2, b1, b2, ws);
  combine2<<<D_ + 1, D_, 0, stream>>>(W3, b3, ws, ws);
  fused<<<(T_ * B_) / ROWS, 256, 0, stream>>>(indices, lengths, tables, ws, out);
}

// Round 3
// 341.014 us; speedup vs baseline: 1.0039x; 1.0039x over previous
//
#include <hip/hip_runtime.h>

// TestEBCModel: jagged embedding gather + SUM pool (T=4,B=8192,L=50,VOCAB=100000,D=128)
// followed by 3 stacked Linear(D,D) with no activation.
// Affine fold: M = W1^T W2^T W3^T, c = (b1 W2^T + b2) W3^T + b3; fused kernel does
// pool + single matvec per row.
// R3: ROWS=8 / grid=4096 (2 residency rounds -> HW repacking), dynamic intra-block
// bag assignment via LDS atomic (wave-level balance), pooled stored row-major
// (contiguous ds_write_b64, broadcast reads), single merged combine kernel.

#define T_ 4
#define B_ 8192
#define L_ 50
#define VOCAB_ 100000
#define D_ 128
#define ROWS 8         // bags per block in fused kernel
#define NBAGS (T_ * B_)

// ws layout (floats): M[16384] | c[128]
#define WS_M  0
#define WS_C  16384

// ---- merged combine: M = (W1^T W2^T) W3^T ; c = ((b1 W2^T + b2)) W3^T + b3 ----
// blocks 0..127 compute M row i; block 128 computes c. Branch is block-uniform.
__global__ __launch_bounds__(128) void combine(const float* __restrict__ W1,
                                               const float* __restrict__ W2,
                                               const float* __restrict__ W3,
                                               const float* __restrict__ b1,
                                               const float* __restrict__ b2,
                                               const float* __restrict__ b3,
                                               float* __restrict__ ws) {
  __shared__ float a1[D_];
  const int j = threadIdx.x;
  const int i = blockIdx.x;
  if (i < D_) {
    // a1[m] = A1[i][m] = sum_k W1[k][i] * W2[m][k]   (thread j computes m=j)
    float acc = 0.f;
    for (int k = 0; k < D_; ++k)
      acc += W1[k * D_ + i] * W2[j * D_ + k];
    a1[j] = acc;
    __syncthreads();
    // M[i][j] = sum_m a1[m] * W3[j][m]
    float m = 0.f;
    for (int k = 0; k < D_; ++k)
      m += a1[k] * W3[j * D_ + k];
    ws[WS_M + i * D_ + j] = m;
  } else {
    // c1[j] = b2[j] + sum_k b1[k] W2[j][k] ; c[j] = b3[j] + sum_m c1[m] W3[j][m]
    float c1 = b2[j];
    for (int k = 0; k < D_; ++k)
      c1 += b1[k] * W2[j * D_ + k];
    a1[j] = c1;
    __syncthreads();
    float c = b3[j];
    for (int k = 0; k < D_; ++k)
      c += a1[k] * W3[j * D_ + k];
    ws[WS_C + j] = c;
  }
}

// ---- fused: pool ROWS bags (dynamic wave->bag), then out = pooled @ M + c ----
__global__ __launch_bounds__(256) void fused(const int* __restrict__ indices,
                                             const int* __restrict__ lengths,
                                             const float* __restrict__ tables,
                                             const float* __restrict__ ws,
                                             float* __restrict__ out) {
  __shared__ __align__(16) float pooled_sh[ROWS][D_];  // row-major: b64 writes, broadcast reads
  __shared__ int idx_sh[ROWS][L_];
  __shared__ int len_sh[ROWS];
  __shared__ int bag_ctr;

  const int tid = threadIdx.x;
  const int g0  = blockIdx.x * ROWS;

  if (tid == 0) bag_ctr = 0;
  for (int k = tid; k < ROWS * L_; k += 256)
    idx_sh[k / L_][k % L_] = indices[g0 * L_ + k];
  if (tid < ROWS) len_sh[tid] = lengths[g0 + tid];
  __syncthreads();

  // phase 1: waves pull bags from the LDS counter until exhausted.
  // One bag per wave; float2 per lane -> one instr = full 512B row; unroll 8.
  {
    const int lane = tid & 63;
    const int d0   = lane * 2;
    const int t    = g0 >> 13;            // table id; block never spans tables (8 | 8192)
    const float* __restrict__ tab = tables + (size_t)t * (VOCAB_ * D_) + d0;

    for (;;) {
      int pos = 0;
      if (lane == 0) pos = atomicAdd(&bag_ctr, 1);
      pos = __shfl(pos, 0, 64);
      if (pos >= ROWS) break;
      const int len = len_sh[pos];
      const int* __restrict__ il = idx_sh[pos];
      float ax = 0.f, ay = 0.f;
      int l = 0;
      for (; l + 7 < len; l += 8) {
        const int i0 = il[l + 0], i1 = il[l + 1], i2 = il[l + 2], i3 = il[l + 3];
        const int i4 = il[l + 4], i5 = il[l + 5], i6 = il[l + 6], i7 = il[l + 7];
        const float2 v0 = *(const float2*)(tab + (size_t)i0 * D_);
        const float2 v1 = *(const float2*)(tab + (size_t)i1 * D_);
        const float2 v2 = *(const float2*)(tab + (size_t)i2 * D_);
        const float2 v3 = *(const float2*)(tab + (size_t)i3 * D_);
        const float2 v4 = *(const float2*)(tab + (size_t)i4 * D_);
        const float2 v5 = *(const float2*)(tab + (size_t)i5 * D_);
        const float2 v6 = *(const float2*)(tab + (size_t)i6 * D_);
        const float2 v7 = *(const float2*)(tab + (size_t)i7 * D_);
        ax += v0.x; ay += v0.y;  ax += v1.x; ay += v1.y;
        ax += v2.x; ay += v2.y;  ax += v3.x; ay += v3.y;
        ax += v4.x; ay += v4.y;  ax += v5.x; ay += v5.y;
        ax += v6.x; ay += v6.y;  ax += v7.x; ay += v7.y;
      }
      for (; l + 1 < len; l += 2) {
        const float2 va = *(const float2*)(tab + (size_t)il[l] * D_);
        const float2 vb = *(const float2*)(tab + (size_t)il[l + 1] * D_);
        ax += va.x; ay += va.y;  ax += vb.x; ay += vb.y;
      }
      if (l < len) {
        const float2 v = *(const float2*)(tab + (size_t)il[l] * D_);
        ax += v.x; ay += v.y;
      }
      *(float2*)&pooled_sh[pos][d0] = make_float2(ax, ay);  // contiguous ds_write_b64
    }
  }
  __syncthreads();

  // phase 2: out[g0+r][j] = c[j] + sum_i pooled[r][i] * M[i][j]
  // per i: 1 coalesced M load (wave reads 256B, L2-hot), 4 broadcast LDS reads, 4 FMAs.
  const int j  = tid & (D_ - 1);
  const int rh = (tid >> 7) * 4;          // rows rh..rh+3
  const float* __restrict__ Mg = ws + WS_M;
  const float cj = ws[WS_C + j];
  float acc0 = cj, acc1 = cj, acc2 = cj, acc3 = cj;
#pragma unroll 4
  for (int i = 0; i < D_; ++i) {
    const float m = Mg[i * D_ + j];
    acc0 += pooled_sh[rh + 0][i] * m;
    acc1 += pooled_sh[rh + 1][i] * m;
    acc2 += pooled_sh[rh + 2][i] * m;
    acc3 += pooled_sh[rh + 3][i] * m;
  }
  out[(size_t)(g0 + rh + 0) * D_ + j] = acc0;
  out[(size_t)(g0 + rh + 1) * D_ + j] = acc1;
  out[(size_t)(g0 + rh + 2) * D_ + j] = acc2;
  out[(size_t)(g0 + rh + 3) * D_ + j] = acc3;
}

extern "C" void kernel_launch(void* const* d_in, const int* in_sizes, int n_in,
                              void* d_out, int out_size, void* d_ws, size_t ws_size,
                              hipStream_t stream) {
  const int*   indices = (const int*)d_in[0];
  const int*   lengths = (const int*)d_in[1];
  const float* tables  = (const float*)d_in[2];
  const float* W1      = (const float*)d_in[3];
  const float* b1      = (const float*)d_in[4];
  const float* W2      = (const float*)d_in[5];
  const float* b2      = (const float*)d_in[6];
  const float* W3      = (const float*)d_in[7];
  const float* b3      = (const float*)d_in[8];
  float*       out     = (float*)d_out;
  float*       ws      = (float*)d_ws;

  combine<<<D_ + 1, D_, 0, stream>>>(W1, W2, W3, b1, b2, b3, ws);
  fused<<<NBAGS / ROWS, 256, 0, stream>>>(indices, lengths, tables, ws, out);
}